// Round 6
// baseline (326.181 us; speedup 1.0000x reference)
//
#include <hip/hip_runtime.h>
#include <stdint.h>
#include <math.h>

typedef short short8 __attribute__((ext_vector_type(8)));
typedef float float4v __attribute__((ext_vector_type(4)));

static __device__ __forceinline__ float bf2f(uint16_t u) {
    union { uint32_t i; float f; } x; x.i = ((uint32_t)u) << 16; return x.f;
}
static __device__ __forceinline__ uint16_t f2bf(float f) {
    union { float f; uint32_t i; } x; x.f = f;
    uint32_t u = x.i;
    u += 0x7FFFu + ((u >> 16) & 1u);   // RNE
    return (uint16_t)(u >> 16);
}
static __device__ __forceinline__ uint16_t f2bf_sane(float f) {
    uint16_t u = f2bf(f);
    if ((u & 0x7F80u) == 0x7F80u) u = 0;
    return u;
}
static __device__ __forceinline__ float san_f32(float f) {
    union { float f; uint32_t i; } x; x.f = f;
    if (((x.i >> 23) & 0xFFu) == 0xFFu) return 0.f;
    return x.f;
}
static __device__ __forceinline__ void gll16(const void* g, void* l) {
    __builtin_amdgcn_global_load_lds((const __attribute__((address_space(1))) void*)g,
                                     (__attribute__((address_space(3))) void*)l,
                                     16, 0, 0);
}
static __device__ __forceinline__ short8 load8(const void* p, size_t off, int fp32) {
    if (!fp32) return *(const short8*)((const uint16_t*)p + off);
    const float* f = (const float*)p + off;
    const float4v a = *(const float4v*)f;
    const float4v b = *(const float4v*)(f + 4);
    short8 r;
    r[0] = (short)f2bf(a[0]); r[1] = (short)f2bf(a[1]);
    r[2] = (short)f2bf(a[2]); r[3] = (short)f2bf(a[3]);
    r[4] = (short)f2bf(b[0]); r[5] = (short)f2bf(b[1]);
    r[6] = (short)f2bf(b[2]); r[7] = (short)f2bf(b[3]);
    return r;
}

// ---------------------------------------------------------------------------
// dtype probe
// ---------------------------------------------------------------------------
__global__ __launch_bounds__(256) void detect_kernel(const uint16_t* qx, int* flag)
{
    __shared__ int s;
    const int tid = threadIdx.x;
    if (tid == 0) s = 0;
    __syncthreads();
    int bad = 0;
#pragma unroll 8
    for (int i = 0; i < 64; ++i) {
        const uint16_t u = qx[tid * 64 + i];
        bad |= ((u & 0x7F80u) == 0x7F80u) ? 1 : 0;
    }
    if (bad) atomicOr(&s, 1);
    __syncthreads();
    if (tid == 0) *flag = s;
}

// ---------------------------------------------------------------------------
// mask bitpack: maskPAD[4096][2048] int32 -> mask64[4096][32] uint64 (1 MB)
// ---------------------------------------------------------------------------
__global__ __launch_bounds__(256) void pack_kernel(
    const int* __restrict__ mask, uint64_t* __restrict__ mask64)
{
    const int wave = threadIdx.x >> 6, lane = threadIdx.x & 63;
    const int row = blockIdx.x * 4 + wave;
    const int* src = mask + (size_t)row * 2048;
#pragma unroll 4
    for (int j = 0; j < 32; ++j) {
        const int m = src[j * 64 + lane];
        const uint64_t bal = __ballot(m != 0);
        if (lane == 0) mask64[(size_t)row * 32 + j] = bal;
    }
}

// ---------------------------------------------------------------------------
// convert externals to canonical bf16 in ws — only needed when mode==1 (fp32)
// ---------------------------------------------------------------------------
__global__ __launch_bounds__(256) void convert_kernel(
    const void* qx, const void* kx, const void* vx,
    const void* wq, const void* wk, const void* wv, const void* wo,
    const void* bq, const void* bk, const void* bv, const void* bo,
    uint16_t* cIn, uint16_t* cW, uint16_t* cB, const int* flag)
{
    const int mode = *flag;
    if (!mode) return;   // raw tensors are already bf16; GEMMs read them directly
    const int z = blockIdx.z;
    const int idx8 = blockIdx.x * 256 + threadIdx.x;
    if (z < 3) {
        const void* src = (z == 0) ? qx : (z == 1) ? kx : vx;
        uint16_t* dst = cIn + (size_t)z * 4194304;
        if (idx8 < 524288)
            *(short8*)(dst + (size_t)idx8 * 8) = load8(src, (size_t)idx8 * 8, 1);
    } else if (z < 7) {
        const int t = z - 3;
        const void* src = (t == 0) ? wq : (t == 1) ? wk : (t == 2) ? wv : wo;
        uint16_t* dst = cW + (size_t)t * 1048576;
        if (idx8 < 131072)
            *(short8*)(dst + (size_t)idx8 * 8) = load8(src, (size_t)idx8 * 8, 1);
    } else {
        if (idx8 < 128) {
#pragma unroll
            for (int t = 0; t < 4; ++t) {
                const void* src = (t == 0) ? bq : (t == 1) ? bk : (t == 2) ? bv : bo;
                *(short8*)(cB + t * 1024 + idx8 * 8) = load8(src, (size_t)idx8 * 8, 1);
            }
        }
    }
}

// ---------------------------------------------------------------------------
// m97-style GEMM: C[4096][1024] = A @ W^T + bias, all-bf16, fp32 acc.
// ---------------------------------------------------------------------------
template <int MI, int NI>
static __device__ __forceinline__ void gemm_tile(
    const uint16_t* __restrict__ A, const uint16_t* __restrict__ W,
    const uint16_t* __restrict__ bias, void* __restrict__ C,
    int c_fp32, float out_scale)
{
    constexpr int TM = MI * 32, TN = NI * 32;
    __shared__ __align__(16) uint16_t sA[TM * 32];
    __shared__ __align__(16) uint16_t sB[TN * 32];

    const int tid  = threadIdx.x;
    const int wave = tid >> 6;
    const int lane = tid & 63;
    const int quad = lane >> 4;
    const int l15  = lane & 15;
    const int m0 = blockIdx.y * TM;
    const int n0 = blockIdx.x * TN;
    const int wm = (wave >> 1) * (MI * 16);
    const int wn = (wave & 1) * (NI * 16);
    const int r16 = lane >> 2;
    const int ch  = lane & 3;

    float4v acc[MI][NI] = {};

    for (int k0 = 0; k0 < 1024; k0 += 32) {
        __syncthreads();
#pragma unroll
        for (int g = wave; g < TM / 16; g += 4)
            gll16(A + (size_t)(m0 + g * 16 + r16) * 1024 + k0 + ch * 8,
                  (char*)sA + (size_t)g * 1024);
#pragma unroll
        for (int g = wave; g < TN / 16; g += 4)
            gll16(W + (size_t)(n0 + g * 16 + r16) * 1024 + k0 + ch * 8,
                  (char*)sB + (size_t)g * 1024);
        asm volatile("s_waitcnt vmcnt(0)" ::: "memory");
        __syncthreads();

        short8 af[MI], bfr[NI];
#pragma unroll
        for (int i = 0; i < MI; ++i)
            af[i] = *(const short8*)&sA[(wm + i * 16 + l15) * 32 + quad * 8];
#pragma unroll
        for (int j = 0; j < NI; ++j)
            bfr[j] = *(const short8*)&sB[(wn + j * 16 + l15) * 32 + quad * 8];
#pragma unroll
        for (int mi = 0; mi < MI; ++mi)
#pragma unroll
            for (int ni = 0; ni < NI; ++ni)
                acc[mi][ni] = __builtin_amdgcn_mfma_f32_16x16x32_bf16(
                    af[mi], bfr[ni], acc[mi][ni], 0, 0, 0);
    }

#pragma unroll
    for (int ni = 0; ni < NI; ++ni) {
        const int n = n0 + wn + ni * 16 + l15;
        const float bv = bf2f(bias[n]);
#pragma unroll
        for (int mi = 0; mi < MI; ++mi) {
            const int mbase = m0 + wm + mi * 16 + quad * 4;
#pragma unroll
            for (int r = 0; r < 4; ++r) {
                const float v = (acc[mi][ni][r] + bv) * out_scale;
                const size_t idx = (size_t)(mbase + r) * 1024 + n;
                if (c_fp32) ((float*)C)[idx] = san_f32(v);
                else        ((uint16_t*)C)[idx] = f2bf_sane(v);
            }
        }
    }
}

__global__ __launch_bounds__(256) void qkv_kernel(
    const uint16_t* rqx, const uint16_t* rkx, const uint16_t* rvx,
    const uint16_t* rwq, const uint16_t* rwk, const uint16_t* rwv,
    const uint16_t* rbq, const uint16_t* rbk, const uint16_t* rbv,
    const uint16_t* cIn, const uint16_t* cW, const uint16_t* cB,
    uint16_t* Q, uint16_t* K, uint16_t* V, const int* flag)
{
    const int mode = *flag;
    const int z = blockIdx.z;
    const uint16_t* A = mode ? cIn + (size_t)z * 4194304
                             : ((z == 0) ? rqx : (z == 1) ? rkx : rvx);
    const uint16_t* W = mode ? cW + (size_t)z * 1048576
                             : ((z == 0) ? rwq : (z == 1) ? rwk : rwv);
    const uint16_t* b = mode ? cB + z * 1024
                             : ((z == 0) ? rbq : (z == 1) ? rbk : rbv);
    uint16_t* C = (z == 0) ? Q : (z == 1) ? K : V;
    const float sc = (z == 0) ? 0.125f : 1.0f;   // fold 1/sqrt(DK) into Q
    gemm_tile<4, 4>(A, W, b, C, 0, sc);
}

__global__ __launch_bounds__(256) void out_kernel(
    const uint16_t* Z, const uint16_t* rwo, const uint16_t* rbo,
    const uint16_t* cW, const uint16_t* cB, void* out, const int* flag)
{
    const int mode = *flag;
    const uint16_t* W = mode ? cW + 3 * 1048576 : rwo;
    const uint16_t* b = mode ? cB + 3 * 1024 : rbo;
    gemm_tile<2, 4>(Z, W, b, out, mode, 1.0f);
}

// ---------------------------------------------------------------------------
// V transpose: V[B*L][H*64] -> Vt[B][H][64][L]
// ---------------------------------------------------------------------------
__global__ __launch_bounds__(256) void vtrans_kernel(
    const uint16_t* __restrict__ Vp, uint16_t* __restrict__ Vt)
{
    __shared__ __align__(16) uint16_t t[64][72];
    const int tid = threadIdx.x;
    const int lt = blockIdx.x, h = blockIdx.y, b = blockIdx.z;
#pragma unroll
    for (int p = 0; p < 2; ++p) {
        const int r = p * 32 + (tid >> 3);
        const int c = (tid & 7) * 8;
        *(short8*)&t[r][c] =
            *(const short8*)(Vp + (size_t)(b * 2048 + lt * 64 + r) * 1024 + h * 64 + c);
    }
    __syncthreads();
#pragma unroll
    for (int p = 0; p < 2; ++p) {
        const int d = p * 32 + (tid >> 3);
        const int c = (tid & 7) * 8;
        short8 v;
#pragma unroll
        for (int j = 0; j < 8; ++j) v[j] = (short)t[c + j][d];
        *(short8*)(Vt + (size_t)((b * 16 + h) * 64 + d) * 2048 + lt * 64 + c) = v;
    }
}

// ---------------------------------------------------------------------------
// Flash attention v3: each wave handles 32 q-rows (2 m-tiles) so every K/V
// frag ds_read feeds two MFMAs. Block = 128 q-rows. Fixed-ref softmax;
// exp+mask in C-layout; P through LDS as bf16; row sums via ones-MFMA.
// ---------------------------------------------------------------------------
#define VS 72

__global__ __launch_bounds__(256) void attn_kernel(
    const uint16_t* __restrict__ Q, const uint16_t* __restrict__ Kp,
    const uint16_t* __restrict__ Vt, const uint64_t* __restrict__ mask64,
    uint16_t* __restrict__ Z)
{
    __shared__ __align__(16) uint16_t sK[64 * VS];
    __shared__ __align__(16) uint16_t sV[64 * VS];
    __shared__ __align__(16) uint16_t sP[4][32 * VS];

    const int tid = threadIdx.x;
    const int wave = tid >> 6, lane = tid & 63;
    const int quad = lane >> 4, l15 = lane & 15;
    const int qt = blockIdx.x, h = blockIdx.y, b = blockIdx.z;
    const int q0 = qt * 128;
    const int qw = q0 + wave * 32;

    const int srow = tid >> 2;
    const int sc0  = tid & 3;

    // Q frags directly global->VGPR (Q pre-scaled by 0.125 in qkv epilogue)
    short8 qf[2][2];
#pragma unroll
    for (int mi = 0; mi < 2; ++mi)
#pragma unroll
        for (int kk = 0; kk < 2; ++kk)
            qf[mi][kk] = *(const short8*)(Q + (size_t)(b * 2048 + qw + mi * 16 + l15) * 1024
                                            + h * 64 + (quad + 4 * kk) * 8);

    // packed-mask row pointers for this lane's C-layout rows (mi,r)
    const uint64_t* mrow[2][4];
#pragma unroll
    for (int mi = 0; mi < 2; ++mi)
#pragma unroll
        for (int r = 0; r < 4; ++r)
            mrow[mi][r] = mask64 + (size_t)(b * 2048 + qw + mi * 16 + quad * 4 + r) * 32;

    short8 ones;
#pragma unroll
    for (int j = 0; j < 8; ++j) ones[j] = (short)0x3F80;   // bf16 1.0

    float4v oacc[2][4] = {};
    float4v lacc[2] = {};

    for (int kt = 0; kt < 32; ++kt) {
        const int k0 = kt * 64;
        const short8 kx0 = *(const short8*)(Kp + (size_t)(b * 2048 + k0 + srow) * 1024 + h * 64 + sc0 * 8);
        const short8 kx1 = *(const short8*)(Kp + (size_t)(b * 2048 + k0 + srow) * 1024 + h * 64 + (sc0 + 4) * 8);
        const short8 vx0 = *(const short8*)(Vt + (size_t)((b * 16 + h) * 64 + srow) * 2048 + k0 + sc0 * 8);
        const short8 vx1 = *(const short8*)(Vt + (size_t)((b * 16 + h) * 64 + srow) * 2048 + k0 + (sc0 + 4) * 8);
        __syncthreads();   // prior iteration's sK/sV reads done
        *(short8*)&sK[srow * VS + sc0 * 8]       = kx0;
        *(short8*)&sK[srow * VS + (sc0 + 4) * 8] = kx1;
        *(short8*)&sV[srow * VS + sc0 * 8]       = vx0;
        *(short8*)&sV[srow * VS + (sc0 + 4) * 8] = vx1;
        __syncthreads();

        // S = Q @ K^T : each kf read feeds both m-tiles
        float4v sacc[2][4] = {};
#pragma unroll
        for (int ni = 0; ni < 4; ++ni) {
            const int row = ni * 16 + l15;
#pragma unroll
            for (int kk = 0; kk < 2; ++kk) {
                const short8 kf = *(const short8*)&sK[row * VS + (quad + 4 * kk) * 8];
                sacc[0][ni] = __builtin_amdgcn_mfma_f32_16x16x32_bf16(qf[0][kk], kf, sacc[0][ni], 0, 0, 0);
                sacc[1][ni] = __builtin_amdgcn_mfma_f32_16x16x32_bf16(qf[1][kk], kf, sacc[1][ni], 0, 0, 0);
            }
        }

        // mask + exp in C-layout, write P as bf16
        uint16_t* Pw = &sP[wave][0];
#pragma unroll
        for (int mi = 0; mi < 2; ++mi) {
            uint64_t mw[4];
#pragma unroll
            for (int r = 0; r < 4; ++r) mw[r] = mrow[mi][r][kt];
#pragma unroll
            for (int ni = 0; ni < 4; ++ni)
#pragma unroll
                for (int r = 0; r < 4; ++r) {
                    const float p = ((mw[r] >> (ni * 16 + l15)) & 1ull)
                                        ? __expf(sacc[mi][ni][r]) : 0.f;
                    Pw[(mi * 16 + quad * 4 + r) * VS + ni * 16 + l15] = f2bf(p);
                }
        }
        asm volatile("s_waitcnt lgkmcnt(0)" ::: "memory");
        short8 pf[2][2];
#pragma unroll
        for (int mi = 0; mi < 2; ++mi)
#pragma unroll
            for (int kk = 0; kk < 2; ++kk)
                pf[mi][kk] = *(const short8*)&Pw[(mi * 16 + l15) * VS + (quad + 4 * kk) * 8];
        asm volatile("" ::: "memory");

        // O += P @ V ; l += P @ ones : each vf read feeds both m-tiles
#pragma unroll
        for (int ni = 0; ni < 4; ++ni) {
            const int row = ni * 16 + l15;
#pragma unroll
            for (int kk = 0; kk < 2; ++kk) {
                const short8 vf = *(const short8*)&sV[row * VS + (quad + 4 * kk) * 8];
                oacc[0][ni] = __builtin_amdgcn_mfma_f32_16x16x32_bf16(pf[0][kk], vf, oacc[0][ni], 0, 0, 0);
                oacc[1][ni] = __builtin_amdgcn_mfma_f32_16x16x32_bf16(pf[1][kk], vf, oacc[1][ni], 0, 0, 0);
            }
        }
#pragma unroll
        for (int mi = 0; mi < 2; ++mi)
#pragma unroll
            for (int kk = 0; kk < 2; ++kk)
                lacc[mi] = __builtin_amdgcn_mfma_f32_16x16x32_bf16(pf[mi][kk], ones, lacc[mi], 0, 0, 0);
    }

    // normalize + store Z[b, l, h*64+d]
#pragma unroll
    for (int mi = 0; mi < 2; ++mi)
#pragma unroll
        for (int r = 0; r < 4; ++r) {
            const float inv = 1.0f / fmaxf(lacc[mi][r], 1e-37f);
            const int qrow = qw + mi * 16 + quad * 4 + r;
#pragma unroll
            for (int ni = 0; ni < 4; ++ni) {
                const float v = oacc[mi][ni][r] * inv;
                Z[(size_t)(b * 2048 + qrow) * 1024 + h * 64 + ni * 16 + l15] = f2bf_sane(v);
            }
        }
}

// ---------------------------------------------------------------------------
// ws layout (MB): 0 cIn[3x8] | 24 cW[4x2] | 32 cB+flag | 33 Q 8 | 41 K 8 |
// 49 V 8 | 57 mask64 1 | Vt reuses cIn[1], Z reuses cIn[0].
// ---------------------------------------------------------------------------
extern "C" void kernel_launch(void* const* d_in, const int* in_sizes, int n_in,
                              void* d_out, int out_size, void* d_ws, size_t ws_size,
                              hipStream_t stream)
{
    const void* qx  = d_in[0];
    const void* kx  = d_in[1];
    const void* vx  = d_in[2];
    const int*  msk = (const int*)d_in[3];

    char* ws = (char*)d_ws;
    const size_t MB = 1024 * 1024;
    uint16_t* cIn = (uint16_t*)(ws);
    uint16_t* cW  = (uint16_t*)(ws + 24 * MB);
    uint16_t* cB  = (uint16_t*)(ws + 32 * MB);
    int*      flg = (int*)(ws + 32 * MB + 16 * 1024);
    uint16_t* Qb  = (uint16_t*)(ws + 33 * MB);
    uint16_t* Kb  = (uint16_t*)(ws + 41 * MB);
    uint16_t* Vb  = (uint16_t*)(ws + 49 * MB);
    uint64_t* m64 = (uint64_t*)(ws + 57 * MB);
    uint16_t* Vt  = (uint16_t*)(ws + 8 * MB);
    uint16_t* Zb  = (uint16_t*)(ws);

    detect_kernel<<<1, 256, 0, stream>>>((const uint16_t*)qx, flg);
    pack_kernel<<<1024, 256, 0, stream>>>(msk, m64);
    convert_kernel<<<dim3(2048, 1, 8), 256, 0, stream>>>(
        qx, kx, vx, d_in[4], d_in[6], d_in[8], d_in[10],
        d_in[5], d_in[7], d_in[9], d_in[11], cIn, cW, cB, flg);
    qkv_kernel<<<dim3(8, 32, 3), 256, 0, stream>>>(
        (const uint16_t*)qx, (const uint16_t*)kx, (const uint16_t*)vx,
        (const uint16_t*)d_in[4], (const uint16_t*)d_in[6], (const uint16_t*)d_in[8],
        (const uint16_t*)d_in[5], (const uint16_t*)d_in[7], (const uint16_t*)d_in[9],
        cIn, cW, cB, Qb, Kb, Vb, flg);
    vtrans_kernel<<<dim3(32, 16, 2), 256, 0, stream>>>(Vb, Vt);
    attn_kernel<<<dim3(16, 16, 2), 256, 0, stream>>>(Qb, Kb, Vt, m64, Zb);
    out_kernel<<<dim3(8, 64), 256, 0, stream>>>(
        Zb, (const uint16_t*)d_in[10], (const uint16_t*)d_in[11], cW, cB, d_out, flg);
}

// Round 7
// 325.296 us; speedup vs baseline: 1.0027x; 1.0027x over previous
//
#include <hip/hip_runtime.h>
#include <stdint.h>
#include <math.h>

typedef short short8 __attribute__((ext_vector_type(8)));
typedef float float4v __attribute__((ext_vector_type(4)));

static __device__ __forceinline__ float bf2f(uint16_t u) {
    union { uint32_t i; float f; } x; x.i = ((uint32_t)u) << 16; return x.f;
}
static __device__ __forceinline__ uint16_t f2bf(float f) {
    union { float f; uint32_t i; } x; x.f = f;
    uint32_t u = x.i;
    u += 0x7FFFu + ((u >> 16) & 1u);   // RNE
    return (uint16_t)(u >> 16);
}
static __device__ __forceinline__ uint16_t f2bf_sane(float f) {
    uint16_t u = f2bf(f);
    if ((u & 0x7F80u) == 0x7F80u) u = 0;
    return u;
}
static __device__ __forceinline__ float san_f32(float f) {
    union { float f; uint32_t i; } x; x.f = f;
    if (((x.i >> 23) & 0xFFu) == 0xFFu) return 0.f;
    return x.f;
}
static __device__ __forceinline__ void gll16(const void* g, void* l) {
    __builtin_amdgcn_global_load_lds((const __attribute__((address_space(1))) void*)g,
                                     (__attribute__((address_space(3))) void*)l,
                                     16, 0, 0);
}
static __device__ __forceinline__ short8 load8(const void* p, size_t off, int fp32) {
    if (!fp32) return *(const short8*)((const uint16_t*)p + off);
    const float* f = (const float*)p + off;
    const float4v a = *(const float4v*)f;
    const float4v b = *(const float4v*)(f + 4);
    short8 r;
    r[0] = (short)f2bf(a[0]); r[1] = (short)f2bf(a[1]);
    r[2] = (short)f2bf(a[2]); r[3] = (short)f2bf(a[3]);
    r[4] = (short)f2bf(b[0]); r[5] = (short)f2bf(b[1]);
    r[6] = (short)f2bf(b[2]); r[7] = (short)f2bf(b[3]);
    return r;
}

// ---------------------------------------------------------------------------
// dtype probe
// ---------------------------------------------------------------------------
__global__ __launch_bounds__(256) void detect_kernel(const uint16_t* qx, int* flag)
{
    __shared__ int s;
    const int tid = threadIdx.x;
    if (tid == 0) s = 0;
    __syncthreads();
    int bad = 0;
#pragma unroll 8
    for (int i = 0; i < 64; ++i) {
        const uint16_t u = qx[tid * 64 + i];
        bad |= ((u & 0x7F80u) == 0x7F80u) ? 1 : 0;
    }
    if (bad) atomicOr(&s, 1);
    __syncthreads();
    if (tid == 0) *flag = s;
}

// ---------------------------------------------------------------------------
// mask bitpack: maskPAD[4096][2048] int32 -> mask64[4096][32] uint64 (1 MB)
// ---------------------------------------------------------------------------
__global__ __launch_bounds__(256) void pack_kernel(
    const int* __restrict__ mask, uint64_t* __restrict__ mask64)
{
    const int wave = threadIdx.x >> 6, lane = threadIdx.x & 63;
    const int row = blockIdx.x * 4 + wave;
    const int* src = mask + (size_t)row * 2048;
#pragma unroll 4
    for (int j = 0; j < 32; ++j) {
        const int m = src[j * 64 + lane];
        const uint64_t bal = __ballot(m != 0);
        if (lane == 0) mask64[(size_t)row * 32 + j] = bal;
    }
}

// ---------------------------------------------------------------------------
// convert externals to canonical bf16 in ws — only does work when mode==1
// ---------------------------------------------------------------------------
__global__ __launch_bounds__(256) void convert_kernel(
    const void* qx, const void* kx, const void* vx,
    const void* wq, const void* wk, const void* wv, const void* wo,
    const void* bq, const void* bk, const void* bv, const void* bo,
    uint16_t* cIn, uint16_t* cW, uint16_t* cB, const int* flag)
{
    const int mode = *flag;
    if (!mode) return;
    const int z = blockIdx.z;
    if (z < 3) {
        const void* src = (z == 0) ? qx : (z == 1) ? kx : vx;
        uint16_t* dst = cIn + (size_t)z * 4194304;
#pragma unroll
        for (int it = 0; it < 8; ++it) {
            const int idx8 = (blockIdx.x * 8 + it) * 256 + threadIdx.x;
            *(short8*)(dst + (size_t)idx8 * 8) = load8(src, (size_t)idx8 * 8, 1);
        }
    } else if (z < 7) {
        const int t = z - 3;
        const void* src = (t == 0) ? wq : (t == 1) ? wk : (t == 2) ? wv : wo;
        uint16_t* dst = cW + (size_t)t * 1048576;
#pragma unroll
        for (int it = 0; it < 2; ++it) {
            const int idx8 = (blockIdx.x * 2 + it) * 256 + threadIdx.x;
            *(short8*)(dst + (size_t)idx8 * 8) = load8(src, (size_t)idx8 * 8, 1);
        }
    } else {
        const int idx8 = blockIdx.x * 256 + threadIdx.x;
        if (idx8 < 128) {
#pragma unroll
            for (int t = 0; t < 4; ++t) {
                const void* src = (t == 0) ? bq : (t == 1) ? bk : (t == 2) ? bv : bo;
                *(short8*)(cB + t * 1024 + idx8 * 8) = load8(src, (size_t)idx8 * 8, 1);
            }
        }
    }
}

// ---------------------------------------------------------------------------
// m97-style GEMM: C[4096][1024] = A @ W^T + bias, all-bf16, fp32 acc.
// (structure untouched — m97-validated; K-loop tweaks measured neutral m131-141)
// ---------------------------------------------------------------------------
template <int MI, int NI>
static __device__ __forceinline__ void gemm_tile(
    const uint16_t* __restrict__ A, const uint16_t* __restrict__ W,
    const uint16_t* __restrict__ bias, void* __restrict__ C,
    int c_fp32, float out_scale)
{
    constexpr int TM = MI * 32, TN = NI * 32;
    __shared__ __align__(16) uint16_t sA[TM * 32];
    __shared__ __align__(16) uint16_t sB[TN * 32];

    const int tid  = threadIdx.x;
    const int wave = tid >> 6;
    const int lane = tid & 63;
    const int quad = lane >> 4;
    const int l15  = lane & 15;
    const int m0 = blockIdx.y * TM;
    const int n0 = blockIdx.x * TN;
    const int wm = (wave >> 1) * (MI * 16);
    const int wn = (wave & 1) * (NI * 16);
    const int r16 = lane >> 2;
    const int ch  = lane & 3;

    float4v acc[MI][NI] = {};

    for (int k0 = 0; k0 < 1024; k0 += 32) {
        __syncthreads();
#pragma unroll
        for (int g = wave; g < TM / 16; g += 4)
            gll16(A + (size_t)(m0 + g * 16 + r16) * 1024 + k0 + ch * 8,
                  (char*)sA + (size_t)g * 1024);
#pragma unroll
        for (int g = wave; g < TN / 16; g += 4)
            gll16(W + (size_t)(n0 + g * 16 + r16) * 1024 + k0 + ch * 8,
                  (char*)sB + (size_t)g * 1024);
        asm volatile("s_waitcnt vmcnt(0)" ::: "memory");
        __syncthreads();

        short8 af[MI], bfr[NI];
#pragma unroll
        for (int i = 0; i < MI; ++i)
            af[i] = *(const short8*)&sA[(wm + i * 16 + l15) * 32 + quad * 8];
#pragma unroll
        for (int j = 0; j < NI; ++j)
            bfr[j] = *(const short8*)&sB[(wn + j * 16 + l15) * 32 + quad * 8];
#pragma unroll
        for (int mi = 0; mi < MI; ++mi)
#pragma unroll
            for (int ni = 0; ni < NI; ++ni)
                acc[mi][ni] = __builtin_amdgcn_mfma_f32_16x16x32_bf16(
                    af[mi], bfr[ni], acc[mi][ni], 0, 0, 0);
    }

#pragma unroll
    for (int ni = 0; ni < NI; ++ni) {
        const int n = n0 + wn + ni * 16 + l15;
        const float bv = bf2f(bias[n]);
#pragma unroll
        for (int mi = 0; mi < MI; ++mi) {
            const int mbase = m0 + wm + mi * 16 + quad * 4;
#pragma unroll
            for (int r = 0; r < 4; ++r) {
                const float v = (acc[mi][ni][r] + bv) * out_scale;
                const size_t idx = (size_t)(mbase + r) * 1024 + n;
                if (c_fp32) ((float*)C)[idx] = san_f32(v);
                else        ((uint16_t*)C)[idx] = f2bf_sane(v);
            }
        }
    }
}

__global__ __launch_bounds__(256) void qkv_kernel(
    const uint16_t* rqx, const uint16_t* rkx, const uint16_t* rvx,
    const uint16_t* rwq, const uint16_t* rwk, const uint16_t* rwv,
    const uint16_t* rbq, const uint16_t* rbk, const uint16_t* rbv,
    const uint16_t* cIn, const uint16_t* cW, const uint16_t* cB,
    uint16_t* Q, uint16_t* K, uint16_t* V, const int* flag)
{
    const int mode = *flag;
    const int z = blockIdx.z;
    const uint16_t* A = mode ? cIn + (size_t)z * 4194304
                             : ((z == 0) ? rqx : (z == 1) ? rkx : rvx);
    const uint16_t* W = mode ? cW + (size_t)z * 1048576
                             : ((z == 0) ? rwq : (z == 1) ? rwk : rwv);
    const uint16_t* b = mode ? cB + z * 1024
                             : ((z == 0) ? rbq : (z == 1) ? rbk : rbv);
    uint16_t* C = (z == 0) ? Q : (z == 1) ? K : V;
    const float sc = (z == 0) ? 0.125f : 1.0f;   // fold 1/sqrt(DK) into Q
    gemm_tile<4, 4>(A, W, b, C, 0, sc);
}

__global__ __launch_bounds__(256) void out_kernel(
    const uint16_t* Z, const uint16_t* rwo, const uint16_t* rbo,
    const uint16_t* cW, const uint16_t* cB, void* out, const int* flag)
{
    const int mode = *flag;
    const uint16_t* W = mode ? cW + 3 * 1048576 : rwo;
    const uint16_t* b = mode ? cB + 3 * 1024 : rbo;
    gemm_tile<2, 4>(Z, W, b, out, mode, 1.0f);
}

// ---------------------------------------------------------------------------
// V transpose: V[B*L][H*64] -> Vt[B][H][64][L]
// ---------------------------------------------------------------------------
__global__ __launch_bounds__(256) void vtrans_kernel(
    const uint16_t* __restrict__ Vp, uint16_t* __restrict__ Vt)
{
    __shared__ __align__(16) uint16_t t[64][72];
    const int tid = threadIdx.x;
    const int lt = blockIdx.x, h = blockIdx.y, b = blockIdx.z;
#pragma unroll
    for (int p = 0; p < 2; ++p) {
        const int r = p * 32 + (tid >> 3);
        const int c = (tid & 7) * 8;
        *(short8*)&t[r][c] =
            *(const short8*)(Vp + (size_t)(b * 2048 + lt * 64 + r) * 1024 + h * 64 + c);
    }
    __syncthreads();
#pragma unroll
    for (int p = 0; p < 2; ++p) {
        const int d = p * 32 + (tid >> 3);
        const int c = (tid & 7) * 8;
        short8 v;
#pragma unroll
        for (int j = 0; j < 8; ++j) v[j] = (short)t[c + j][d];
        *(short8*)(Vt + (size_t)((b * 16 + h) * 64 + d) * 2048 + lt * 64 + c) = v;
    }
}

// ---------------------------------------------------------------------------
// Flash attention v4: kt-SPLIT for occupancy. Grid z = b + 2*half; each block
// does 16 of 32 kt iters and writes UNNORMALIZED partials (O bf16, l f32).
// Fixed-ref softmax makes partials additive. 2 m-tiles/wave (DS amortized).
// ---------------------------------------------------------------------------
#define VS 72

__global__ __launch_bounds__(256) void attn_kernel(
    const uint16_t* __restrict__ Q, const uint16_t* __restrict__ Kp,
    const uint16_t* __restrict__ Vt, const uint64_t* __restrict__ mask64,
    uint16_t* __restrict__ Oa, uint16_t* __restrict__ Ob,
    float* __restrict__ lpart)
{
    __shared__ __align__(16) uint16_t sK[64 * VS];
    __shared__ __align__(16) uint16_t sV[64 * VS];
    __shared__ __align__(16) uint16_t sP[4][32 * VS];

    const int tid = threadIdx.x;
    const int wave = tid >> 6, lane = tid & 63;
    const int quad = lane >> 4, l15 = lane & 15;
    const int qt = blockIdx.x, h = blockIdx.y;
    const int b = blockIdx.z & 1, half = blockIdx.z >> 1;
    const int q0 = qt * 128;
    const int qw = q0 + wave * 32;

    const int srow = tid >> 2;
    const int sc0  = tid & 3;

    // Q frags directly global->VGPR (Q pre-scaled by 0.125)
    short8 qf[2][2];
#pragma unroll
    for (int mi = 0; mi < 2; ++mi)
#pragma unroll
        for (int kk = 0; kk < 2; ++kk)
            qf[mi][kk] = *(const short8*)(Q + (size_t)(b * 2048 + qw + mi * 16 + l15) * 1024
                                            + h * 64 + (quad + 4 * kk) * 8);

    const uint64_t* mrow[2][4];
#pragma unroll
    for (int mi = 0; mi < 2; ++mi)
#pragma unroll
        for (int r = 0; r < 4; ++r)
            mrow[mi][r] = mask64 + (size_t)(b * 2048 + qw + mi * 16 + quad * 4 + r) * 32;

    short8 ones;
#pragma unroll
    for (int j = 0; j < 8; ++j) ones[j] = (short)0x3F80;   // bf16 1.0

    float4v oacc[2][4] = {};
    float4v lacc[2] = {};

    const int kt_lo = half * 16, kt_hi = kt_lo + 16;
    for (int kt = kt_lo; kt < kt_hi; ++kt) {
        const int k0 = kt * 64;
        const short8 kx0 = *(const short8*)(Kp + (size_t)(b * 2048 + k0 + srow) * 1024 + h * 64 + sc0 * 8);
        const short8 kx1 = *(const short8*)(Kp + (size_t)(b * 2048 + k0 + srow) * 1024 + h * 64 + (sc0 + 4) * 8);
        const short8 vx0 = *(const short8*)(Vt + (size_t)((b * 16 + h) * 64 + srow) * 2048 + k0 + sc0 * 8);
        const short8 vx1 = *(const short8*)(Vt + (size_t)((b * 16 + h) * 64 + srow) * 2048 + k0 + (sc0 + 4) * 8);
        __syncthreads();
        *(short8*)&sK[srow * VS + sc0 * 8]       = kx0;
        *(short8*)&sK[srow * VS + (sc0 + 4) * 8] = kx1;
        *(short8*)&sV[srow * VS + sc0 * 8]       = vx0;
        *(short8*)&sV[srow * VS + (sc0 + 4) * 8] = vx1;
        __syncthreads();

        // S = Q @ K^T : each kf read feeds both m-tiles
        float4v sacc[2][4] = {};
#pragma unroll
        for (int ni = 0; ni < 4; ++ni) {
            const int row = ni * 16 + l15;
#pragma unroll
            for (int kk = 0; kk < 2; ++kk) {
                const short8 kf = *(const short8*)&sK[row * VS + (quad + 4 * kk) * 8];
                sacc[0][ni] = __builtin_amdgcn_mfma_f32_16x16x32_bf16(qf[0][kk], kf, sacc[0][ni], 0, 0, 0);
                sacc[1][ni] = __builtin_amdgcn_mfma_f32_16x16x32_bf16(qf[1][kk], kf, sacc[1][ni], 0, 0, 0);
            }
        }

        // mask + exp in C-layout, write P as bf16
        uint16_t* Pw = &sP[wave][0];
#pragma unroll
        for (int mi = 0; mi < 2; ++mi) {
            uint64_t mw[4];
#pragma unroll
            for (int r = 0; r < 4; ++r) mw[r] = mrow[mi][r][kt];
#pragma unroll
            for (int ni = 0; ni < 4; ++ni)
#pragma unroll
                for (int r = 0; r < 4; ++r) {
                    const float p = ((mw[r] >> (ni * 16 + l15)) & 1ull)
                                        ? __expf(sacc[mi][ni][r]) : 0.f;
                    Pw[(mi * 16 + quad * 4 + r) * VS + ni * 16 + l15] = f2bf(p);
                }
        }
        asm volatile("s_waitcnt lgkmcnt(0)" ::: "memory");
        short8 pf[2][2];
#pragma unroll
        for (int mi = 0; mi < 2; ++mi)
#pragma unroll
            for (int kk = 0; kk < 2; ++kk)
                pf[mi][kk] = *(const short8*)&Pw[(mi * 16 + l15) * VS + (quad + 4 * kk) * 8];
        asm volatile("" ::: "memory");

        // O += P @ V ; l += P @ ones
#pragma unroll
        for (int ni = 0; ni < 4; ++ni) {
            const int row = ni * 16 + l15;
#pragma unroll
            for (int kk = 0; kk < 2; ++kk) {
                const short8 vf = *(const short8*)&sV[row * VS + (quad + 4 * kk) * 8];
                oacc[0][ni] = __builtin_amdgcn_mfma_f32_16x16x32_bf16(pf[0][kk], vf, oacc[0][ni], 0, 0, 0);
                oacc[1][ni] = __builtin_amdgcn_mfma_f32_16x16x32_bf16(pf[1][kk], vf, oacc[1][ni], 0, 0, 0);
            }
        }
#pragma unroll
        for (int mi = 0; mi < 2; ++mi)
#pragma unroll
            for (int kk = 0; kk < 2; ++kk)
                lacc[mi] = __builtin_amdgcn_mfma_f32_16x16x32_bf16(pf[mi][kk], ones, lacc[mi], 0, 0, 0);
    }

    // store UNNORMALIZED partials
    uint16_t* Op = half ? Ob : Oa;
#pragma unroll
    for (int mi = 0; mi < 2; ++mi)
#pragma unroll
        for (int r = 0; r < 4; ++r) {
            const int qrow = qw + mi * 16 + quad * 4 + r;
#pragma unroll
            for (int ni = 0; ni < 4; ++ni)
                Op[(size_t)(b * 2048 + qrow) * 1024 + h * 64 + ni * 16 + l15] = f2bf(oacc[mi][ni][r]);
            if (l15 == 0)
                lpart[half * 65536 + (b * 16 + h) * 2048 + qrow] = lacc[mi][r];
        }
}

// ---------------------------------------------------------------------------
// combine: Z = (Oa + Ob) / (la + lb), in-place over Oa's region.
// ---------------------------------------------------------------------------
__global__ __launch_bounds__(256) void combine_kernel(
    const uint16_t* __restrict__ Oa, const uint16_t* __restrict__ Ob,
    const float* __restrict__ lpart, uint16_t* __restrict__ Z)
{
    const int e8 = blockIdx.x * 256 + threadIdx.x;   // [0, 1M)
    const int flat = e8 * 8;
    const int bh_row = flat >> 10;          // b*2048+row
    const int h = (flat >> 6) & 15;
    const int b = bh_row >> 11;
    const int row = bh_row & 2047;
    const int lidx = (b * 16 + h) * 2048 + row;
    const float inv = 1.0f / fmaxf(lpart[lidx] + lpart[65536 + lidx], 1e-37f);
    const short8 a = *(const short8*)(Oa + flat);
    const short8 c = *(const short8*)(Ob + flat);
    short8 o;
#pragma unroll
    for (int j = 0; j < 8; ++j)
        o[j] = (short)f2bf_sane((bf2f((uint16_t)a[j]) + bf2f((uint16_t)c[j])) * inv);
    *(short8*)(Z + flat) = o;
}

// ---------------------------------------------------------------------------
// ws (MB): 0-8 Oa/Zb (cIn[0] dead after qkv) | 8-16 Vt (cIn[1]) | 16-24 Ob
// (cIn[2]) | 24-32 cW | 32-33 cB+flag | 33-41 Q | 41-49 K | 49-57 Vb (lpart
// f32 1MB at 49 after vtrans) | 57-58 mask64
// ---------------------------------------------------------------------------
extern "C" void kernel_launch(void* const* d_in, const int* in_sizes, int n_in,
                              void* d_out, int out_size, void* d_ws, size_t ws_size,
                              hipStream_t stream)
{
    const void* qx  = d_in[0];
    const void* kx  = d_in[1];
    const void* vx  = d_in[2];
    const int*  msk = (const int*)d_in[3];

    char* ws = (char*)d_ws;
    const size_t MB = 1024 * 1024;
    uint16_t* cIn = (uint16_t*)(ws);
    uint16_t* cW  = (uint16_t*)(ws + 24 * MB);
    uint16_t* cB  = (uint16_t*)(ws + 32 * MB);
    int*      flg = (int*)(ws + 32 * MB + 16 * 1024);
    uint16_t* Qb  = (uint16_t*)(ws + 33 * MB);
    uint16_t* Kb  = (uint16_t*)(ws + 41 * MB);
    uint16_t* Vb  = (uint16_t*)(ws + 49 * MB);
    uint64_t* m64 = (uint64_t*)(ws + 57 * MB);
    uint16_t* Vt  = (uint16_t*)(ws + 8 * MB);    // reuse cIn[1]
    uint16_t* Oa  = (uint16_t*)(ws);             // reuse cIn[0]
    uint16_t* Ob  = (uint16_t*)(ws + 16 * MB);   // reuse cIn[2]
    float*    lp  = (float*)(ws + 49 * MB);      // reuse Vb (dead after vtrans)
    uint16_t* Zb  = Oa;                          // combine writes in place

    detect_kernel<<<1, 256, 0, stream>>>((const uint16_t*)qx, flg);
    pack_kernel<<<1024, 256, 0, stream>>>(msk, m64);
    convert_kernel<<<dim3(256, 1, 8), 256, 0, stream>>>(
        qx, kx, vx, d_in[4], d_in[6], d_in[8], d_in[10],
        d_in[5], d_in[7], d_in[9], d_in[11], cIn, cW, cB, flg);
    qkv_kernel<<<dim3(8, 32, 3), 256, 0, stream>>>(
        (const uint16_t*)qx, (const uint16_t*)kx, (const uint16_t*)vx,
        (const uint16_t*)d_in[4], (const uint16_t*)d_in[6], (const uint16_t*)d_in[8],
        (const uint16_t*)d_in[5], (const uint16_t*)d_in[7], (const uint16_t*)d_in[9],
        cIn, cW, cB, Qb, Kb, Vb, flg);
    vtrans_kernel<<<dim3(32, 16, 2), 256, 0, stream>>>(Vb, Vt);
    attn_kernel<<<dim3(16, 16, 4), 256, 0, stream>>>(Qb, Kb, Vt, m64, Oa, Ob, lp);
    combine_kernel<<<4096, 256, 0, stream>>>(Oa, Ob, lp, Zb);
    out_kernel<<<dim3(8, 64), 256, 0, stream>>>(
        Zb, (const uint16_t*)d_in[10], (const uint16_t*)d_in[11], cW, cB, d_out, flg);
}

// Round 8
// 305.484 us; speedup vs baseline: 1.0678x; 1.0649x over previous
//
#include <hip/hip_runtime.h>
#include <stdint.h>
#include <math.h>

typedef short short8 __attribute__((ext_vector_type(8)));
typedef short short4v __attribute__((ext_vector_type(4)));
typedef float float4v __attribute__((ext_vector_type(4)));

static __device__ __forceinline__ float bf2f(uint16_t u) {
    union { uint32_t i; float f; } x; x.i = ((uint32_t)u) << 16; return x.f;
}
static __device__ __forceinline__ uint16_t f2bf(float f) {
    union { float f; uint32_t i; } x; x.f = f;
    uint32_t u = x.i;
    u += 0x7FFFu + ((u >> 16) & 1u);   // RNE
    return (uint16_t)(u >> 16);
}
static __device__ __forceinline__ uint16_t f2bf_sane(float f) {
    uint16_t u = f2bf(f);
    if ((u & 0x7F80u) == 0x7F80u) u = 0;
    return u;
}
static __device__ __forceinline__ float san_f32(float f) {
    union { float f; uint32_t i; } x; x.f = f;
    if (((x.i >> 23) & 0xFFu) == 0xFFu) return 0.f;
    return x.f;
}
static __device__ __forceinline__ void gll16(const void* g, void* l) {
    __builtin_amdgcn_global_load_lds((const __attribute__((address_space(1))) void*)g,
                                     (__attribute__((address_space(3))) void*)l,
                                     16, 0, 0);
}
static __device__ __forceinline__ short8 load8(const void* p, size_t off, int fp32) {
    if (!fp32) return *(const short8*)((const uint16_t*)p + off);
    const float* f = (const float*)p + off;
    const float4v a = *(const float4v*)f;
    const float4v b = *(const float4v*)(f + 4);
    short8 r;
    r[0] = (short)f2bf(a[0]); r[1] = (short)f2bf(a[1]);
    r[2] = (short)f2bf(a[2]); r[3] = (short)f2bf(a[3]);
    r[4] = (short)f2bf(b[0]); r[5] = (short)f2bf(b[1]);
    r[6] = (short)f2bf(b[2]); r[7] = (short)f2bf(b[3]);
    return r;
}

// 16x16x16 bf16 MFMA: builtin if present, else raw asm (hazard nops at use site)
static __device__ __forceinline__ float4v mfma16_bf16(short4v a, short4v b, float4v c) {
#if __has_builtin(__builtin_amdgcn_mfma_f32_16x16x16bf16_1k)
    return __builtin_amdgcn_mfma_f32_16x16x16bf16_1k(a, b, c, 0, 0, 0);
#else
    float4v d = c;
    asm volatile("v_mfma_f32_16x16x16_bf16 %0, %1, %2, %0"
                 : "+v"(d) : "v"(a), "v"(b));
    return d;
#endif
}

// ---------------------------------------------------------------------------
// dtype probe
// ---------------------------------------------------------------------------
__global__ __launch_bounds__(256) void detect_kernel(const uint16_t* qx, int* flag)
{
    __shared__ int s;
    const int tid = threadIdx.x;
    if (tid == 0) s = 0;
    __syncthreads();
    int bad = 0;
#pragma unroll 8
    for (int i = 0; i < 64; ++i) {
        const uint16_t u = qx[tid * 64 + i];
        bad |= ((u & 0x7F80u) == 0x7F80u) ? 1 : 0;
    }
    if (bad) atomicOr(&s, 1);
    __syncthreads();
    if (tid == 0) *flag = s;
}

// ---------------------------------------------------------------------------
// mask bitpack: maskPAD[4096][2048] int32 -> mask64[4096][32] uint64 (1 MB)
// ---------------------------------------------------------------------------
__global__ __launch_bounds__(256) void pack_kernel(
    const int* __restrict__ mask, uint64_t* __restrict__ mask64)
{
    const int wave = threadIdx.x >> 6, lane = threadIdx.x & 63;
    const int row = blockIdx.x * 4 + wave;
    const int* src = mask + (size_t)row * 2048;
#pragma unroll 4
    for (int j = 0; j < 32; ++j) {
        const int m = src[j * 64 + lane];
        const uint64_t bal = __ballot(m != 0);
        if (lane == 0) mask64[(size_t)row * 32 + j] = bal;
    }
}

// ---------------------------------------------------------------------------
// convert externals to canonical bf16 in ws — only does work when mode==1
// ---------------------------------------------------------------------------
__global__ __launch_bounds__(256) void convert_kernel(
    const void* qx, const void* kx, const void* vx,
    const void* wq, const void* wk, const void* wv, const void* wo,
    const void* bq, const void* bk, const void* bv, const void* bo,
    uint16_t* cIn, uint16_t* cW, uint16_t* cB, const int* flag)
{
    const int mode = *flag;
    if (!mode) return;
    const int z = blockIdx.z;
    if (z < 3) {
        const void* src = (z == 0) ? qx : (z == 1) ? kx : vx;
        uint16_t* dst = cIn + (size_t)z * 4194304;
#pragma unroll
        for (int it = 0; it < 8; ++it) {
            const int idx8 = (blockIdx.x * 8 + it) * 256 + threadIdx.x;
            *(short8*)(dst + (size_t)idx8 * 8) = load8(src, (size_t)idx8 * 8, 1);
        }
    } else if (z < 7) {
        const int t = z - 3;
        const void* src = (t == 0) ? wq : (t == 1) ? wk : (t == 2) ? wv : wo;
        uint16_t* dst = cW + (size_t)t * 1048576;
#pragma unroll
        for (int it = 0; it < 2; ++it) {
            const int idx8 = (blockIdx.x * 2 + it) * 256 + threadIdx.x;
            *(short8*)(dst + (size_t)idx8 * 8) = load8(src, (size_t)idx8 * 8, 1);
        }
    } else {
        const int idx8 = blockIdx.x * 256 + threadIdx.x;
        if (idx8 < 128) {
#pragma unroll
            for (int t = 0; t < 4; ++t) {
                const void* src = (t == 0) ? bq : (t == 1) ? bk : (t == 2) ? bv : bo;
                *(short8*)(cB + t * 1024 + idx8 * 8) = load8(src, (size_t)idx8 * 8, 1);
            }
        }
    }
}

// ---------------------------------------------------------------------------
// m97-style GEMM: C[4096][1024] = A @ W^T + bias, all-bf16, fp32 acc.
// ---------------------------------------------------------------------------
template <int MI, int NI>
static __device__ __forceinline__ void gemm_tile(
    const uint16_t* __restrict__ A, const uint16_t* __restrict__ W,
    const uint16_t* __restrict__ bias, void* __restrict__ C,
    int c_fp32, float out_scale)
{
    constexpr int TM = MI * 32, TN = NI * 32;
    __shared__ __align__(16) uint16_t sA[TM * 32];
    __shared__ __align__(16) uint16_t sB[TN * 32];

    const int tid  = threadIdx.x;
    const int wave = tid >> 6;
    const int lane = tid & 63;
    const int quad = lane >> 4;
    const int l15  = lane & 15;
    const int m0 = blockIdx.y * TM;
    const int n0 = blockIdx.x * TN;
    const int wm = (wave >> 1) * (MI * 16);
    const int wn = (wave & 1) * (NI * 16);
    const int r16 = lane >> 2;
    const int ch  = lane & 3;

    float4v acc[MI][NI] = {};

    for (int k0 = 0; k0 < 1024; k0 += 32) {
        __syncthreads();
#pragma unroll
        for (int g = wave; g < TM / 16; g += 4)
            gll16(A + (size_t)(m0 + g * 16 + r16) * 1024 + k0 + ch * 8,
                  (char*)sA + (size_t)g * 1024);
#pragma unroll
        for (int g = wave; g < TN / 16; g += 4)
            gll16(W + (size_t)(n0 + g * 16 + r16) * 1024 + k0 + ch * 8,
                  (char*)sB + (size_t)g * 1024);
        asm volatile("s_waitcnt vmcnt(0)" ::: "memory");
        __syncthreads();

        short8 af[MI], bfr[NI];
#pragma unroll
        for (int i = 0; i < MI; ++i)
            af[i] = *(const short8*)&sA[(wm + i * 16 + l15) * 32 + quad * 8];
#pragma unroll
        for (int j = 0; j < NI; ++j)
            bfr[j] = *(const short8*)&sB[(wn + j * 16 + l15) * 32 + quad * 8];
#pragma unroll
        for (int mi = 0; mi < MI; ++mi)
#pragma unroll
            for (int ni = 0; ni < NI; ++ni)
                acc[mi][ni] = __builtin_amdgcn_mfma_f32_16x16x32_bf16(
                    af[mi], bfr[ni], acc[mi][ni], 0, 0, 0);
    }

#pragma unroll
    for (int ni = 0; ni < NI; ++ni) {
        const int n = n0 + wn + ni * 16 + l15;
        const float bv = bf2f(bias[n]);
#pragma unroll
        for (int mi = 0; mi < MI; ++mi) {
            const int mbase = m0 + wm + mi * 16 + quad * 4;
#pragma unroll
            for (int r = 0; r < 4; ++r) {
                const float v = (acc[mi][ni][r] + bv) * out_scale;
                const size_t idx = (size_t)(mbase + r) * 1024 + n;
                if (c_fp32) ((float*)C)[idx] = san_f32(v);
                else        ((uint16_t*)C)[idx] = f2bf_sane(v);
            }
        }
    }
}

__global__ __launch_bounds__(256) void qkv_kernel(
    const uint16_t* rqx, const uint16_t* rkx, const uint16_t* rvx,
    const uint16_t* rwq, const uint16_t* rwk, const uint16_t* rwv,
    const uint16_t* rbq, const uint16_t* rbk, const uint16_t* rbv,
    const uint16_t* cIn, const uint16_t* cW, const uint16_t* cB,
    uint16_t* Q, uint16_t* K, uint16_t* V, const int* flag)
{
    const int mode = *flag;
    const int z = blockIdx.z;
    const uint16_t* A = mode ? cIn + (size_t)z * 4194304
                             : ((z == 0) ? rqx : (z == 1) ? rkx : rvx);
    const uint16_t* W = mode ? cW + (size_t)z * 1048576
                             : ((z == 0) ? rwq : (z == 1) ? rwk : rwv);
    const uint16_t* b = mode ? cB + z * 1024
                             : ((z == 0) ? rbq : (z == 1) ? rbk : rbv);
    uint16_t* C = (z == 0) ? Q : (z == 1) ? K : V;
    const float sc = (z == 0) ? 0.125f : 1.0f;   // fold 1/sqrt(DK) into Q
    gemm_tile<4, 4>(A, W, b, C, 0, sc);
}

__global__ __launch_bounds__(256) void out_kernel(
    const uint16_t* Z, const uint16_t* rwo, const uint16_t* rbo,
    const uint16_t* cW, const uint16_t* cB, void* out, const int* flag)
{
    const int mode = *flag;
    const uint16_t* W = mode ? cW + 3 * 1048576 : rwo;
    const uint16_t* b = mode ? cB + 3 * 1024 : rbo;
    gemm_tile<2, 4>(Z, W, b, out, mode, 1.0f);
}

// ---------------------------------------------------------------------------
// V transpose: V[B*L][H*64] -> Vt[B][H][64][L]
// ---------------------------------------------------------------------------
__global__ __launch_bounds__(256) void vtrans_kernel(
    const uint16_t* __restrict__ Vp, uint16_t* __restrict__ Vt)
{
    __shared__ __align__(16) uint16_t t[64][72];
    const int tid = threadIdx.x;
    const int lt = blockIdx.x, h = blockIdx.y, b = blockIdx.z;
#pragma unroll
    for (int p = 0; p < 2; ++p) {
        const int r = p * 32 + (tid >> 3);
        const int c = (tid & 7) * 8;
        *(short8*)&t[r][c] =
            *(const short8*)(Vp + (size_t)(b * 2048 + lt * 64 + r) * 1024 + h * 64 + c);
    }
    __syncthreads();
#pragma unroll
    for (int p = 0; p < 2; ++p) {
        const int d = p * 32 + (tid >> 3);
        const int c = (tid & 7) * 8;
        short8 v;
#pragma unroll
        for (int j = 0; j < 8; ++j) v[j] = (short)t[c + j][d];
        *(short8*)(Vt + (size_t)((b * 16 + h) * 64 + d) * 2048 + lt * 64 + c) = v;
    }
}

// ---------------------------------------------------------------------------
// Flash attention v5: TRANSPOSE TRICK. S^T = mfma(K,Q) puts q on col=l15:
// one mask word per lane; exp in C-layout regs IS the B-frag of a 16x16x16
// MFMA, so PV needs no LDS transform. O^T accumulated; l = lane-local sums
// + 2 epilogue shuffles. kt-split partials as in v4. LDS: sK+sV only (18KB).
// ---------------------------------------------------------------------------
#define VS 72

__global__ __launch_bounds__(256, 4) void attn_kernel(
    const uint16_t* __restrict__ Q, const uint16_t* __restrict__ Kp,
    const uint16_t* __restrict__ Vt, const uint64_t* __restrict__ mask64,
    uint16_t* __restrict__ Oa, uint16_t* __restrict__ Ob,
    float* __restrict__ lpart)
{
    __shared__ __align__(16) uint16_t sK[64 * VS];
    __shared__ __align__(16) uint16_t sV[64 * VS];

    const int tid = threadIdx.x;
    const int wave = tid >> 6, lane = tid & 63;
    const int quad = lane >> 4, l15 = lane & 15;
    const int qt = blockIdx.x, h = blockIdx.y;
    const int b = blockIdx.z & 1, half = blockIdx.z >> 1;
    const int q0 = qt * 128;
    const int qw = q0 + wave * 32;

    const int srow = tid >> 2;
    const int sc0  = tid & 3;

    // Q frags (B-operand: rows q=l15): direct global->VGPR, pre-scaled by 0.125
    short8 qf[2][2];
#pragma unroll
    for (int mi = 0; mi < 2; ++mi)
#pragma unroll
        for (int kk = 0; kk < 2; ++kk)
            qf[mi][kk] = *(const short8*)(Q + (size_t)(b * 2048 + qw + mi * 16 + l15) * 1024
                                            + h * 64 + (quad + 4 * kk) * 8);

    // one packed-mask row per lane per m-tile (q = qw + mj*16 + l15)
    const uint64_t* mrow[2];
#pragma unroll
    for (int mj = 0; mj < 2; ++mj)
        mrow[mj] = mask64 + (size_t)(b * 2048 + qw + mj * 16 + l15) * 32;

    float4v oaccT[4][2] = {};   // O^T tiles [di][mj]: row=d, col=q
    float lsum[2] = {};

    const int kt_lo = half * 16, kt_hi = kt_lo + 16;
    for (int kt = kt_lo; kt < kt_hi; ++kt) {
        const int k0 = kt * 64;
        const short8 kx0 = *(const short8*)(Kp + (size_t)(b * 2048 + k0 + srow) * 1024 + h * 64 + sc0 * 8);
        const short8 kx1 = *(const short8*)(Kp + (size_t)(b * 2048 + k0 + srow) * 1024 + h * 64 + (sc0 + 4) * 8);
        const short8 vx0 = *(const short8*)(Vt + (size_t)((b * 16 + h) * 64 + srow) * 2048 + k0 + sc0 * 8);
        const short8 vx1 = *(const short8*)(Vt + (size_t)((b * 16 + h) * 64 + srow) * 2048 + k0 + (sc0 + 4) * 8);
        const uint64_t mw0 = mrow[0][kt];
        const uint64_t mw1 = mrow[1][kt];
        __syncthreads();
        *(short8*)&sK[srow * VS + sc0 * 8]       = kx0;
        *(short8*)&sK[srow * VS + (sc0 + 4) * 8] = kx1;
        *(short8*)&sV[srow * VS + sc0 * 8]       = vx0;
        *(short8*)&sV[srow * VS + (sc0 + 4) * 8] = vx1;
        __syncthreads();

        // S^T = K @ Q^T : A = K-frag (rows kpos), B = Q-frag (rows q)
        float4v sacc[2][4] = {};
#pragma unroll
        for (int ni = 0; ni < 4; ++ni) {
            const int row = ni * 16 + l15;
#pragma unroll
            for (int kk = 0; kk < 2; ++kk) {
                const short8 kf = *(const short8*)&sK[row * VS + (quad + 4 * kk) * 8];
                sacc[0][ni] = __builtin_amdgcn_mfma_f32_16x16x32_bf16(kf, qf[0][kk], sacc[0][ni], 0, 0, 0);
                sacc[1][ni] = __builtin_amdgcn_mfma_f32_16x16x32_bf16(kf, qf[1][kk], sacc[1][ni], 0, 0, 0);
            }
        }

        // mask + exp in place: lane's q = l15 (fixed), kpos = ni*16+quad*4+r.
        // Resulting quartets are exactly 16x16x16 B-frags.
        short4v pf[2][4];
#pragma unroll
        for (int mj = 0; mj < 2; ++mj) {
            const uint64_t mw = mj ? mw1 : mw0;
#pragma unroll
            for (int ni = 0; ni < 4; ++ni) {
                const uint32_t nib = (uint32_t)(mw >> (ni * 16 + quad * 4)) & 0xFu;
                short4v t;
#pragma unroll
                for (int r = 0; r < 4; ++r) {
                    const float p = (nib >> r) & 1u ? __expf(sacc[mj][ni][r]) : 0.f;
                    lsum[mj] += p;
                    t[r] = (short)f2bf(p);
                }
                pf[mj][ni] = t;
            }
        }

        // O^T += V^T @ P^T : A = Vt-frag (rows d), B = P-frag (rows q)
#pragma unroll
        for (int di = 0; di < 4; ++di) {
            const int row = di * 16 + l15;
#pragma unroll
            for (int ni = 0; ni < 4; ++ni) {
                const short4v vf = *(const short4v*)&sV[row * VS + ni * 16 + quad * 4];
                oaccT[di][0] = mfma16_bf16(vf, pf[0][ni], oaccT[di][0]);
                oaccT[di][1] = mfma16_bf16(vf, pf[1][ni], oaccT[di][1]);
            }
        }
    }

#if !__has_builtin(__builtin_amdgcn_mfma_f32_16x16x16bf16_1k)
    asm volatile("s_nop 7\ns_nop 7\ns_nop 7" ::: "memory");   // MFMA->VALU hazard
#endif

    // l: sum quads (lanes l15, l15+16, l15+32, l15+48 hold disjoint kpos)
#pragma unroll
    for (int mj = 0; mj < 2; ++mj) {
        lsum[mj] += __shfl_xor(lsum[mj], 16);
        lsum[mj] += __shfl_xor(lsum[mj], 32);
    }

    // store unnormalized partials: O^T lane element (d=di*16+quad*4+r, q=mj*16+l15)
    uint16_t* Op = half ? Ob : Oa;
#pragma unroll
    for (int mj = 0; mj < 2; ++mj) {
        const int qrow = qw + mj * 16 + l15;
#pragma unroll
        for (int di = 0; di < 4; ++di) {
            short4v o;
#pragma unroll
            for (int r = 0; r < 4; ++r) o[r] = (short)f2bf(oaccT[di][mj][r]);
            *(short4v*)(Op + (size_t)(b * 2048 + qrow) * 1024 + h * 64 + di * 16 + quad * 4) = o;
        }
        if (quad == 0)
            lpart[half * 65536 + (b * 16 + h) * 2048 + qrow] = lsum[mj];
    }
}

// ---------------------------------------------------------------------------
// combine: Z = (Oa + Ob) / (la + lb), in-place over Oa's region.
// ---------------------------------------------------------------------------
__global__ __launch_bounds__(256) void combine_kernel(
    const uint16_t* __restrict__ Oa, const uint16_t* __restrict__ Ob,
    const float* __restrict__ lpart, uint16_t* __restrict__ Z)
{
    const int e8 = blockIdx.x * 256 + threadIdx.x;   // [0, 1M)
    const int flat = e8 * 8;
    const int bh_row = flat >> 10;          // b*2048+row
    const int h = (flat >> 6) & 15;
    const int b = bh_row >> 11;
    const int row = bh_row & 2047;
    const int lidx = (b * 16 + h) * 2048 + row;
    const float inv = 1.0f / fmaxf(lpart[lidx] + lpart[65536 + lidx], 1e-37f);
    const short8 a = *(const short8*)(Oa + flat);
    const short8 c = *(const short8*)(Ob + flat);
    short8 o;
#pragma unroll
    for (int j = 0; j < 8; ++j)
        o[j] = (short)f2bf_sane((bf2f((uint16_t)a[j]) + bf2f((uint16_t)c[j])) * inv);
    *(short8*)(Z + flat) = o;
}

// ---------------------------------------------------------------------------
// ws (MB): 0-8 Oa/Zb | 8-16 Vt | 16-24 Ob | 24-32 cW | 32-33 cB+flag |
// 33-41 Q | 41-49 K | 49-57 Vb (lpart after vtrans) | 57-58 mask64
// ---------------------------------------------------------------------------
extern "C" void kernel_launch(void* const* d_in, const int* in_sizes, int n_in,
                              void* d_out, int out_size, void* d_ws, size_t ws_size,
                              hipStream_t stream)
{
    const void* qx  = d_in[0];
    const void* kx  = d_in[1];
    const void* vx  = d_in[2];
    const int*  msk = (const int*)d_in[3];

    char* ws = (char*)d_ws;
    const size_t MB = 1024 * 1024;
    uint16_t* cIn = (uint16_t*)(ws);
    uint16_t* cW  = (uint16_t*)(ws + 24 * MB);
    uint16_t* cB  = (uint16_t*)(ws + 32 * MB);
    int*      flg = (int*)(ws + 32 * MB + 16 * 1024);
    uint16_t* Qb  = (uint16_t*)(ws + 33 * MB);
    uint16_t* Kb  = (uint16_t*)(ws + 41 * MB);
    uint16_t* Vb  = (uint16_t*)(ws + 49 * MB);
    uint64_t* m64 = (uint64_t*)(ws + 57 * MB);
    uint16_t* Vt  = (uint16_t*)(ws + 8 * MB);    // reuse cIn[1]
    uint16_t* Oa  = (uint16_t*)(ws);             // reuse cIn[0]
    uint16_t* Ob  = (uint16_t*)(ws + 16 * MB);   // reuse cIn[2]
    float*    lp  = (float*)(ws + 49 * MB);      // reuse Vb (dead after vtrans)
    uint16_t* Zb  = Oa;                          // combine writes in place

    detect_kernel<<<1, 256, 0, stream>>>((const uint16_t*)qx, flg);
    pack_kernel<<<1024, 256, 0, stream>>>(msk, m64);
    convert_kernel<<<dim3(256, 1, 8), 256, 0, stream>>>(
        qx, kx, vx, d_in[4], d_in[6], d_in[8], d_in[10],
        d_in[5], d_in[7], d_in[9], d_in[11], cIn, cW, cB, flg);
    qkv_kernel<<<dim3(8, 32, 3), 256, 0, stream>>>(
        (const uint16_t*)qx, (const uint16_t*)kx, (const uint16_t*)vx,
        (const uint16_t*)d_in[4], (const uint16_t*)d_in[6], (const uint16_t*)d_in[8],
        (const uint16_t*)d_in[5], (const uint16_t*)d_in[7], (const uint16_t*)d_in[9],
        cIn, cW, cB, Qb, Kb, Vb, flg);
    vtrans_kernel<<<dim3(32, 16, 2), 256, 0, stream>>>(Vb, Vt);
    attn_kernel<<<dim3(16, 16, 4), 256, 0, stream>>>(Qb, Kb, Vt, m64, Oa, Ob, lp);
    combine_kernel<<<4096, 256, 0, stream>>>(Oa, Ob, lp, Zb);
    out_kernel<<<dim3(8, 64), 256, 0, stream>>>(
        Zb, (const uint16_t*)d_in[10], (const uint16_t*)d_in[11], cW, cB, d_out, flg);
}